// Round 9
// baseline (611.455 us; speedup 1.0000x reference)
//
#include <hip/hip_runtime.h>
#include <cstdio>

// ---------------------------------------------------------------------------
// BiLSTM  B=64, T=512, D=256, H=256
//   R12: TWO kernels total (was 6) --
//   k_prep: fused {x->bf16 | Wih gate-permuted bf16 | bias vectors |
//           Whh int8 quant+pack}; all parts independent, flat-grid dispatch.
//   k_rec:  per-WG fused GEMM prologue + recurrence. WG (b,d) computes ITS
//           OWN xproj slice (rows < ceil(len/128)*128 only -- k_rec never
//           reads t>=len), drains vmcnt + barrier (same-WG global
//           write->read is coherent), then runs the R8-champion recurrence
//           (int8 matvec on the matrix pipe, x2-unrolled, 1 barrier/step).
//           Removes the standalone full-GPU GEMM pass (~80-100us wall) and
//           3 launch boundaries for ~15us of prologue on the critical WG.
// ---------------------------------------------------------------------------

typedef unsigned short ushort_t;
typedef __attribute__((ext_vector_type(8))) short short8;
typedef __attribute__((ext_vector_type(4))) float f32x4;
typedef __attribute__((ext_vector_type(4))) int i32x4;

__device__ __forceinline__ ushort_t f2bf(float f) {
    union { float f; unsigned u; } v; v.f = f;
    unsigned r = v.u + 0x7fffu + ((v.u >> 16) & 1u);
    return (ushort_t)(r >> 16);
}
__device__ __forceinline__ float bf2f(ushort_t h) {
    union { unsigned u; float f; } v; v.u = ((unsigned)h) << 16;
    return v.f;
}

__device__ __forceinline__ float fexp2(float x) {
#if __has_builtin(__builtin_amdgcn_exp2f)
    return __builtin_amdgcn_exp2f(x);
#else
    return exp2f(x);
#endif
}
__device__ __forceinline__ float frcp(float x) {
#if __has_builtin(__builtin_amdgcn_rcpf)
    return __builtin_amdgcn_rcpf(x);
#else
    return 1.0f / x;
#endif
}
__device__ __forceinline__ float fsig(float x) {
    return frcp(1.0f + fexp2(-1.44269504089f * x));
}
__device__ __forceinline__ float ftanh(float x) {
    float e = fexp2(2.88539008178f * x);
    return 1.0f - 2.0f * frcp(e + 1.0f);
}

// LDS-only barrier: drain lgkm (LDS ops) but NOT vmcnt.
__device__ __forceinline__ void lds_barrier() {
    asm volatile("s_waitcnt lgkmcnt(0)\n\ts_barrier" ::: "memory");
}

// Async global->LDS 16B. lds base must be wave-uniform; HW writes lane l's
// 16B at base + l*16 (measured m104/m108). Size arg must be a literal.
__device__ __forceinline__ void async_load16(const void* g, void* l) {
    __builtin_amdgcn_global_load_lds(
        (const __attribute__((address_space(1))) void*)g,
        (__attribute__((address_space(3))) void*)l, 16, 0, 0);
}

// ---------------------------------------------------------------------------
// k_prep: fused preprocessing. Flat grid of 9224 blocks x 256 threads:
//   [0,8192)      : x fp32 -> bf16            (8.4M elems, 4/thread)
//   [8192,8704)   : Wih -> bf16, gate-permuted rows
//   [8704,8712)   : bias vectors
//   [8712,9224)   : Whh -> int8 mfma-fragment pack + scales
__global__ __launch_bounds__(256) void k_prep(
        const float* __restrict__ x, ushort_t* __restrict__ xbf,
        const float* __restrict__ wihf, const float* __restrict__ wihb,
        ushort_t* __restrict__ wihbf,
        const float* __restrict__ bihf, const float* __restrict__ bhhf,
        const float* __restrict__ bihb, const float* __restrict__ bhhb,
        float* __restrict__ biasv,
        const float* __restrict__ whhf, const float* __restrict__ whhb,
        int* __restrict__ wmf, float* __restrict__ fscale4) {
    const int bid = blockIdx.x;
    const int tid = threadIdx.x;
    if (bid < 8192) {
        // ---- x -> bf16
        int i = (bid * 256 + tid) * 4;
        float4 v = *(const float4*)&x[i];
        ushort4 o;
        o.x = f2bf(v.x); o.y = f2bf(v.y); o.z = f2bf(v.z); o.w = f2bf(v.w);
        *(ushort4*)&xbf[i] = o;
    } else if (bid < 8704) {
        // ---- Wih gate-permuted: dst[d][(n&255)*4+(n>>8)][k] = src_d[n][k]
        int local = bid - 8192;              // 0..511
        int d = local >> 8;
        int n = (local & 255) * 4 + (tid >> 6);
        int l = tid & 63;
        const float* src = (d ? wihb : wihf) + (size_t)n * 256;
        float4 v = *(const float4*)&src[l * 4];
        int np = (n & 255) * 4 + (n >> 8);
        ushort4 o;
        o.x = f2bf(v.x); o.y = f2bf(v.y); o.z = f2bf(v.z); o.w = f2bf(v.w);
        *(ushort4*)&wihbf[((size_t)d * 1024 + np) * 256 + l * 4] = o;
    } else if (bid < 8712) {
        // ---- permuted bias vectors
        int i = (bid - 8704) * 256 + tid;    // 0..2047
        int d = i >> 10, n = i & 1023;
        float s = d ? (bihb[n] + bhhb[n]) : (bihf[n] + bhhf[n]);
        biasv[d * 1024 + (n & 255) * 4 + (n >> 8)] = s;
    } else {
        // ---- Whh int8 quant, packed into mfma_i32_16x16x64_i8 A-frag order
        int rowg = (bid - 8712) * 4 + (tid >> 6);   // 0..2047
        int l = tid & 63;                            // = kc
        int d = rowg >> 10;
        int row = rowg & 1023;
        const float* W = (d ? whhb : whhf) + (size_t)row * 256;
        float4 v = *(const float4*)&W[l * 4];
        float m = fmaxf(fmaxf(fabsf(v.x), fabsf(v.y)), fmaxf(fabsf(v.z), fabsf(v.w)));
        #pragma unroll
        for (int off = 32; off > 0; off >>= 1) m = fmaxf(m, __shfl_xor(m, off));
        float inv = (m > 0.0f) ? (127.0f / m) : 0.0f;
        int q0 = __float2int_rn(v.x * inv);
        int q1 = __float2int_rn(v.y * inv);
        int q2 = __float2int_rn(v.z * inv);
        int q3 = __float2int_rn(v.w * inv);
        q0 = min(127, max(-127, q0)); q1 = min(127, max(-127, q1));
        q2 = min(127, max(-127, q2)); q3 = min(127, max(-127, q3));
        int packed = (q0 & 255) | ((q1 & 255) << 8) | ((q2 & 255) << 16) | ((q3 & 255) << 24);
        int j = row & 255, gate = row >> 8;
        int row_p = j * 4 + gate;
        int Mt = row_p >> 4, rl = row_p & 15;
        int Kt = l >> 4, lg = (l >> 2) & 3, dw = l & 3;
        wmf[d * 65536 + ((Mt * 4 + Kt) * 64 + lg * 16 + rl) * 4 + dw] = packed;
        if (l == 0) fscale4[d * 1024 + row_p] = m / (127.0f * 127.0f);
    }
}

// ---------------------------------------------------------------------------
// k_rec: per-WG fused GEMM prologue + recurrence.
// grid (64 batch, 2 dir) x 512 threads (8 waves).
//
// Phase A (GEMM): jobs of 128x128 over this (b,d)'s xproj; wave split
// wm=w&1 (row half) x wn=w>>1 (col quarter): 4x2 fragments/wave. Staging
// via global_load_lds, 2-deep pipeline, counted vmcnt. The LDSOFF swizzle
// is realized by pre-swizzling the global SOURCE col-chunk.
// Phase B (recurrence): R8 champion, byte-identical.
#define LDSOFF(r, kc) ((r) * 32 + ((((kc) + ((r) >> 1)) & 3) * 8))

__global__ __launch_bounds__(512, 2) void k_rec(
        const ushort_t* __restrict__ xbf, const ushort_t* __restrict__ wihbf,
        const float* __restrict__ biasv,
        const int* __restrict__ wmf, const float* __restrict__ fscale4,
        const int* __restrict__ lens,
        ushort_t* __restrict__ xproj, float* __restrict__ out) {
    const int b = blockIdx.x, d = blockIdx.y;
    const int tid = threadIdx.x;
    const int w = tid >> 6, l = tid & 63;
    int len = lens[b];
    if (len < 1) len = 1;
    if (len > 512) len = 512;

    __shared__ ushort_t As[2][4096] __attribute__((aligned(16)));
    __shared__ ushort_t Bs[2][4096] __attribute__((aligned(16)));
    __shared__ char h8[2][256] __attribute__((aligned(16)));

    // ======================= Phase A: GEMM prologue =======================
    {
        const ushort_t* Bmat = wihbf + d * 262144;
        const float* bv = biasv + d * 1024;
        ushort_t* Cb = xproj + (size_t)d * 33554432 + (size_t)b * 524288;
        const int wm = w & 1, wn = w >> 1;

        // Staging geometry: thread covers row r0 = tid>>2 (0..127), LDS
        // col-chunk cb = tid&3; source chunk cs = (cb-(r0>>1))&3 so staged
        // bytes equal the LDSOFF-swizzled layout (reader unchanged).
        const int r0 = tid >> 2, cbk = tid & 3;
        const int cs = (cbk - (r0 >> 1)) & 3;
        const int lw = w * 512;   // wave-uniform LDS base (ushorts)

        const int mcn = (len + 127) >> 7;   // 1..4 m-chunks needed
        for (int mc = 0; mc < mcn; mc++) {
            const ushort_t* Arow =
                &xbf[((size_t)b * 512 + mc * 128 + r0) * 256 + cs * 8];
            for (int nc = 0; nc < 8; nc++) {
                const ushort_t* Brow = &Bmat[(size_t)(nc * 128 + r0) * 256 + cs * 8];
                f32x4 acc[4][2];
                #pragma unroll
                for (int i = 0; i < 4; i++)
                    #pragma unroll
                    for (int jj = 0; jj < 2; jj++)
                        acc[i][jj] = (f32x4){0.f, 0.f, 0.f, 0.f};

#define GEMM_ISSUE(KB, CUR)                                   \
    async_load16(Arow + (KB) * 32, &As[CUR][lw]);             \
    async_load16(Brow + (KB) * 32, &Bs[CUR][lw]);

#define GEMM_COMPUTE(CUR)                                                     \
    {                                                                         \
        short8 af[4], bfr[2];                                                 \
        const int q = l >> 4;                                                 \
        _Pragma("unroll")                                                     \
        for (int mt = 0; mt < 4; mt++) {                                      \
            int rr = wm * 64 + mt * 16 + (l & 15);                            \
            af[mt] = *(const short8*)&As[CUR][LDSOFF(rr, q)];                 \
        }                                                                     \
        _Pragma("unroll")                                                     \
        for (int nt = 0; nt < 2; nt++) {                                      \
            int rr = wn * 32 + nt * 16 + (l & 15);                            \
            bfr[nt] = *(const short8*)&Bs[CUR][LDSOFF(rr, q)];                \
        }                                                                     \
        _Pragma("unroll")                                                     \
        for (int mt = 0; mt < 4; mt++)                                        \
            _Pragma("unroll")                                                 \
            for (int nt = 0; nt < 2; nt++)                                    \
                acc[mt][nt] = __builtin_amdgcn_mfma_f32_16x16x32_bf16(        \
                    af[mt], bfr[nt], acc[mt][nt], 0, 0, 0);                   \
    }

#define GEMM_STEP(KB, CUR, VML, DOISSUE)                                      \
    asm volatile("s_waitcnt vmcnt(" VML ")\n\ts_barrier" ::: "memory");       \
    GEMM_COMPUTE(CUR);                                                        \
    lds_barrier();                                                            \
    if (DOISSUE) { GEMM_ISSUE((KB) + 2, CUR) }

                GEMM_ISSUE(0, 0)
                GEMM_ISSUE(1, 1)
                GEMM_STEP(0, 0, "2", 1)
                GEMM_STEP(1, 1, "2", 1)
                GEMM_STEP(2, 0, "2", 1)
                GEMM_STEP(3, 1, "2", 1)
                GEMM_STEP(4, 0, "2", 1)
                GEMM_STEP(5, 1, "2", 1)
                GEMM_STEP(6, 0, "2", 0)
                GEMM_STEP(7, 1, "0", 0)
#undef GEMM_STEP
#undef GEMM_COMPUTE
#undef GEMM_ISSUE

                #pragma unroll
                for (int nt = 0; nt < 2; nt++) {
                    int n = nc * 128 + wn * 32 + nt * 16 + (l & 15);
                    float bn = bv[n];
                    #pragma unroll
                    for (int mt = 0; mt < 4; mt++) {
                        #pragma unroll
                        for (int rr = 0; rr < 4; rr++) {
                            int m = mc * 128 + wm * 64 + mt * 16 + (l >> 4) * 4 + rr;
                            Cb[(size_t)m * 1024 + n] = f2bf(acc[mt][nt][rr] + bn);
                        }
                    }
                }
            }
        }
    }
    // Phase boundary: xproj stores visible to the whole WG; also a compiler
    // memory fence so the wf loads below cannot hoist into Phase A.
    asm volatile("s_waitcnt vmcnt(0)" ::: "memory");
    __syncthreads();

    // ======================= Phase B: recurrence ==========================
    const int lenm1 = len - 1;
    const bool dneg = (d != 0);
    const ushort_t* xp = xproj + ((size_t)d * 64 + b) * 524288;  // 512*1024

    const int rg = l >> 4;            // 0..3
    const int rg16 = rg * 16;
    const int til = l & 7;
    const bool act = (l & 15) < 8;
    const int j = (w * 8 + til) * 4 + rg;   // unit 0..255

    // 32 A-fragments (128 dwords) pinned in VGPRs.
    i32x4 wf[8][4];
    const int* wb = wmf + d * 65536;
    #pragma unroll
    for (int i = 0; i < 8; i++)
        #pragma unroll
        for (int kt = 0; kt < 4; kt++)
            wf[i][kt] = *(const i32x4*)&wb[(((w * 8 + i) * 4 + kt) * 64 + l) * 4];
    #pragma unroll
    for (int i = 0; i < 8; i++)
        #pragma unroll
        for (int kt = 0; kt < 4; kt++)
            asm volatile("" : "+v"(wf[i][kt]));

    float4 fr = *(const float4*)&fscale4[d * 1024 + 4 * j];   // loop-invariant

    if (tid < 64) ((int*)h8)[tid] = 0;   // zero h8[0]

    // zero-fill this direction's half for t in [len, 512)
    {
        float4 z = {0.f, 0.f, 0.f, 0.f};
        int total4 = (512 - len) * 64;
        for (int i = tid; i < total4; i += 512) {
            int t = len + (i >> 6);
            int c4 = i & 63;
            *(float4*)&out[((size_t)b * 512 + t) * 512 + d * 256 + c4 * 4] = z;
        }
    }
    __syncthreads();

    float c_state = 0.0f;
    const i32x4 z4 = {0, 0, 0, 0};
    // lane-fixed byte pointers; per-step offsets are wave-uniform t*2048.
    const char* const xpl = (const char*)(xp + 4 * j);             // x row t: +t*2048
    char* const outl = (char*)(out + (size_t)b * 262144 + d * 256 + j);  // row t: +t*2048

    // x values for steps s and s+1 (loaded 2 steps ahead, no rotation movs).
    uint2 xe = *(const uint2*)(xpl + (size_t)(dneg ? lenm1 : 0) * 2048);
    uint2 xo;
    {
        int sc = (1 < lenm1) ? 1 : lenm1;
        xo = *(const uint2*)(xpl + (size_t)(dneg ? (lenm1 - sc) : sc) * 2048);
    }

    // One recurrence step at compile-time h8 parity (RB -> read, WB -> write).
    // XREG holds x for this step; it is reloaded with step S+2's row.
#define REC_STEP(RB, WB, XREG, S)                                              \
    do {                                                                       \
        const char* hbp = (const char*)h8[RB];                                 \
        i32x4 h0 = *(const i32x4*)(hbp + rg16);                                \
        i32x4 h1 = *(const i32x4*)(hbp + 64 + rg16);                           \
        i32x4 h2 = *(const i32x4*)(hbp + 128 + rg16);                          \
        i32x4 h3 = *(const i32x4*)(hbp + 192 + rg16);                          \
        uint2 xc = XREG;                                                       \
        {                                                                      \
            int sc2 = (S) + 2; if (sc2 > lenm1) sc2 = lenm1;                   \
            int t2 = dneg ? (lenm1 - sc2) : sc2;                               \
            XREG = *(const uint2*)(xpl + (size_t)t2 * 2048);                   \
        }                                                                      \
        i32x4 acc[8];                                                          \
        _Pragma("unroll")                                                      \
        for (int i = 0; i < 8; i++)                                            \
            acc[i] = __builtin_amdgcn_mfma_i32_16x16x64_i8(wf[i][0], h0, z4, 0, 0, 0); \
        _Pragma("unroll")                                                      \
        for (int i = 0; i < 8; i++)                                            \
            acc[i] = __builtin_amdgcn_mfma_i32_16x16x64_i8(wf[i][1], h1, acc[i], 0, 0, 0); \
        _Pragma("unroll")                                                      \
        for (int i = 0; i < 8; i++)                                            \
            acc[i] = __builtin_amdgcn_mfma_i32_16x16x64_i8(wf[i][2], h2, acc[i], 0, 0, 0); \
        _Pragma("unroll")                                                      \
        for (int i = 0; i < 8; i++)                                            \
            acc[i] = __builtin_amdgcn_mfma_i32_16x16x64_i8(wf[i][3], h3, acc[i], 0, 0, 0); \
        if (act) {                                                             \
            i32x4 q0 = (til & 1) ? acc[1] : acc[0];                            \
            i32x4 q1 = (til & 1) ? acc[3] : acc[2];                            \
            i32x4 q2 = (til & 1) ? acc[5] : acc[4];                            \
            i32x4 q3 = (til & 1) ? acc[7] : acc[6];                            \
            i32x4 r0 = (til & 2) ? q1 : q0;                                    \
            i32x4 r1 = (til & 2) ? q3 : q2;                                    \
            i32x4 u  = (til & 4) ? r1 : r0;                                    \
            float pi = bf2f((ushort_t)(xc.x & 0xffffu)) + fr.x * (float)u.x;   \
            float pf = bf2f((ushort_t)(xc.x >> 16))     + fr.y * (float)u.y;   \
            float pg = bf2f((ushort_t)(xc.y & 0xffffu)) + fr.z * (float)u.z;   \
            float po = bf2f((ushort_t)(xc.y >> 16))     + fr.w * (float)u.w;   \
            float ig = fsig(pi), fg = fsig(pf), gg = ftanh(pg), og = fsig(po); \
            c_state = fg * c_state + ig * gg;                                  \
            float h = og * ftanh(c_state);                                     \
            int qq = __float2int_rn(h * 127.0f);                               \
            qq = min(127, max(-127, qq));                                      \
            h8[WB][j] = (char)qq;                                              \
            int t = dneg ? (lenm1 - (S)) : (S);                                \
            *(float*)(outl + (size_t)t * 2048) = h;                            \
        }                                                                      \
        lds_barrier();                                                         \
    } while (0)

    int s = 0;
    for (; s + 1 < len; s += 2) {
        REC_STEP(0, 1, xe, s);
        REC_STEP(1, 0, xo, s + 1);
    }
    if (len & 1) {
        REC_STEP(0, 1, xe, s);
    }
#undef REC_STEP
}

// ---------------------------------------------------------------------------
extern "C" void kernel_launch(void* const* d_in, const int* in_sizes, int n_in,
                              void* d_out, int out_size, void* d_ws, size_t ws_size,
                              hipStream_t stream) {
    (void)in_sizes; (void)n_in; (void)out_size;
    const float* x    = (const float*)d_in[0];
    const int*   lens = (const int*)d_in[1];
    const float* wihf = (const float*)d_in[2];
    const float* whhf = (const float*)d_in[3];
    const float* bihf = (const float*)d_in[4];
    const float* bhhf = (const float*)d_in[5];
    const float* wihb = (const float*)d_in[6];
    const float* whhb = (const float*)d_in[7];
    const float* bihb = (const float*)d_in[8];
    const float* bhhb = (const float*)d_in[9];
    float* out = (float*)d_out;

    char* ws = (char*)d_ws;
    ushort_t* xbf    = (ushort_t*)(ws + 0);          //  16,777,216 B
    ushort_t* wihbf  = (ushort_t*)(ws + 16777216);   //   1,048,576 B
    float*    biasv  = (float*)(ws + 17825792);      //       8,192 B
    int*      wmf    = (int*)(ws + 17833984);        //     524,288 B
    float*    fscale4= (float*)(ws + 18358272);      //       8,192 B
    ushort_t* xproj  = (ushort_t*)(ws + 18366464);   // 134,217,728 B
    const size_t REQ = 18366464 + 134217728ull;
    if (ws_size < REQ) {
        fprintf(stderr, "kernel_launch: ws too small: %zu < %zu\n", ws_size, REQ);
    }

    k_prep<<<9224, 256, 0, stream>>>(x, xbf, wihf, wihb, wihbf,
                                     bihf, bhhf, bihb, bhhb, biasv,
                                     whhf, whhb, wmf, fscale4);
    k_rec<<<dim3(64, 2), 512, 0, stream>>>(xbf, wihbf, biasv, wmf, fscale4,
                                           lens, xproj, out);
}

// Round 10
// 515.952 us; speedup vs baseline: 1.1851x; 1.1851x over previous
//
#include <hip/hip_runtime.h>
#include <cstdio>

// ---------------------------------------------------------------------------
// BiLSTM  B=64, T=512, D=256, H=256
//   R13 = R11 champion structure (520us) with the three tiny prep kernels
//   fused into one (6 launches -> 4). R12's per-WG GEMM fusion (611us)
//   proved the standalone GEMM's ~80us is per-WG serial pipeline latency,
//   not launch overhead -- fusion onto the k_rec critical path relocates
//   it, so the GEMM stays a standalone full-GPU pass.
//   k_f2bf : x fp32 -> bf16 (bulk, memory-bound)
//   k_prep2: fused {Wih gate-permuted bf16 | bias vectors | Whh int8 pack}
//   k_gemm : tile-skip (t>=len never read) + 2-deep counted-vmcnt pipeline
//   k_rec  : R8 champion, frozen (383us; x2-unrolled, compile-time h8
//            parity, int8 matvec on matrix pipe, 1 lgkm-barrier/step)
// ---------------------------------------------------------------------------

typedef unsigned short ushort_t;
typedef __attribute__((ext_vector_type(8))) short short8;
typedef __attribute__((ext_vector_type(4))) float f32x4;
typedef __attribute__((ext_vector_type(4))) int i32x4;

__device__ __forceinline__ ushort_t f2bf(float f) {
    union { float f; unsigned u; } v; v.f = f;
    unsigned r = v.u + 0x7fffu + ((v.u >> 16) & 1u);
    return (ushort_t)(r >> 16);
}
__device__ __forceinline__ float bf2f(ushort_t h) {
    union { unsigned u; float f; } v; v.u = ((unsigned)h) << 16;
    return v.f;
}

__device__ __forceinline__ float fexp2(float x) {
#if __has_builtin(__builtin_amdgcn_exp2f)
    return __builtin_amdgcn_exp2f(x);
#else
    return exp2f(x);
#endif
}
__device__ __forceinline__ float frcp(float x) {
#if __has_builtin(__builtin_amdgcn_rcpf)
    return __builtin_amdgcn_rcpf(x);
#else
    return 1.0f / x;
#endif
}
__device__ __forceinline__ float fsig(float x) {
    return frcp(1.0f + fexp2(-1.44269504089f * x));
}
__device__ __forceinline__ float ftanh(float x) {
    float e = fexp2(2.88539008178f * x);
    return 1.0f - 2.0f * frcp(e + 1.0f);
}

// LDS-only barrier: drain lgkm (LDS ops) but NOT vmcnt.
__device__ __forceinline__ void lds_barrier() {
    asm volatile("s_waitcnt lgkmcnt(0)\n\ts_barrier" ::: "memory");
}

// Async global->LDS 16B. lds base must be wave-uniform; HW writes lane l's
// 16B at base + l*16 (measured m104/m108). Size arg must be a literal.
__device__ __forceinline__ void async_load16(const void* g, void* l) {
    __builtin_amdgcn_global_load_lds(
        (const __attribute__((address_space(1))) void*)g,
        (__attribute__((address_space(3))) void*)l, 16, 0, 0);
}

// ---------------------------------------------------------------------------
// k_f2bf: fp32 -> bf16 (n multiple of 4)
__global__ __launch_bounds__(256) void k_f2bf(const float* __restrict__ in,
                                              ushort_t* __restrict__ out, int n) {
    int i = (blockIdx.x * 256 + threadIdx.x) * 4;
    if (i + 3 < n) {
        float4 v = *(const float4*)&in[i];
        ushort4 o;
        o.x = f2bf(v.x); o.y = f2bf(v.y); o.z = f2bf(v.z); o.w = f2bf(v.w);
        *(ushort4*)&out[i] = o;
    }
}

// ---------------------------------------------------------------------------
// k_prep2: fused small preprocessing. Flat grid 1032 blocks x 256 threads:
//   [0,512)    : Wih -> bf16, gate-permuted rows
//   [512,520)  : bias vectors
//   [520,1032) : Whh -> int8 mfma-fragment pack + scales
__global__ __launch_bounds__(256) void k_prep2(
        const float* __restrict__ wihf, const float* __restrict__ wihb,
        ushort_t* __restrict__ wihbf,
        const float* __restrict__ bihf, const float* __restrict__ bhhf,
        const float* __restrict__ bihb, const float* __restrict__ bhhb,
        float* __restrict__ biasv,
        const float* __restrict__ whhf, const float* __restrict__ whhb,
        int* __restrict__ wmf, float* __restrict__ fscale4) {
    const int bid = blockIdx.x;
    const int tid = threadIdx.x;
    if (bid < 512) {
        // ---- Wih gate-permuted: dst[d][(n&255)*4+(n>>8)][k] = src_d[n][k]
        int d = bid >> 8;
        int n = (bid & 255) * 4 + (tid >> 6);
        int l = tid & 63;
        const float* src = (d ? wihb : wihf) + (size_t)n * 256;
        float4 v = *(const float4*)&src[l * 4];
        int np = (n & 255) * 4 + (n >> 8);
        ushort4 o;
        o.x = f2bf(v.x); o.y = f2bf(v.y); o.z = f2bf(v.z); o.w = f2bf(v.w);
        *(ushort4*)&wihbf[((size_t)d * 1024 + np) * 256 + l * 4] = o;
    } else if (bid < 520) {
        // ---- permuted bias vectors
        int i = (bid - 512) * 256 + tid;    // 0..2047
        int d = i >> 10, n = i & 1023;
        float s = d ? (bihb[n] + bhhb[n]) : (bihf[n] + bhhf[n]);
        biasv[d * 1024 + (n & 255) * 4 + (n >> 8)] = s;
    } else {
        // ---- Whh int8 quant, packed into mfma_i32_16x16x64_i8 A-frag order
        // Fragment (Mt,Kt): lane rl holds row Mt*16+rl; dwords dw of k-group
        // lg: wmf[d*65536 + ((Mt*4+Kt)*64 + lg*16 + rl)*4 + dw]
        int rowg = (bid - 520) * 4 + (tid >> 6);    // 0..2047
        int l = tid & 63;                            // = kc
        int d = rowg >> 10;
        int row = rowg & 1023;
        const float* W = (d ? whhb : whhf) + (size_t)row * 256;
        float4 v = *(const float4*)&W[l * 4];
        float m = fmaxf(fmaxf(fabsf(v.x), fabsf(v.y)), fmaxf(fabsf(v.z), fabsf(v.w)));
        #pragma unroll
        for (int off = 32; off > 0; off >>= 1) m = fmaxf(m, __shfl_xor(m, off));
        float inv = (m > 0.0f) ? (127.0f / m) : 0.0f;
        int q0 = __float2int_rn(v.x * inv);
        int q1 = __float2int_rn(v.y * inv);
        int q2 = __float2int_rn(v.z * inv);
        int q3 = __float2int_rn(v.w * inv);
        q0 = min(127, max(-127, q0)); q1 = min(127, max(-127, q1));
        q2 = min(127, max(-127, q2)); q3 = min(127, max(-127, q3));
        int packed = (q0 & 255) | ((q1 & 255) << 8) | ((q2 & 255) << 16) | ((q3 & 255) << 24);
        int j = row & 255, gate = row >> 8;
        int row_p = j * 4 + gate;
        int Mt = row_p >> 4, rl = row_p & 15;
        int Kt = l >> 4, lg = (l >> 2) & 3, dw = l & 3;
        wmf[d * 65536 + ((Mt * 4 + Kt) * 64 + lg * 16 + rl) * 4 + dw] = packed;
        if (l == 0) fscale4[d * 1024 + row_p] = m / (127.0f * 127.0f);
    }
}

// ---------------------------------------------------------------------------
// k_gemm: bf16 GEMM, 2-deep pipelined global_load_lds staging + tile skip.
// Wave wv stages bytes wv*1024..+1023 of each half-tile (lane l at +l*16);
// the data loaded for LDS chunk cb of row r is source chunk (cb-(r>>1))&3,
// so staged bytes equal the LDSOFF-swizzled layout (reader unchanged).
#define LDSOFF(r, kc) ((r) * 32 + ((((kc) + ((r) >> 1)) & 3) * 8))

__global__ __launch_bounds__(256) void k_gemm(const ushort_t* __restrict__ A,
                                              const ushort_t* __restrict__ Bw,
                                              const float* __restrict__ biasv,
                                              const int* __restrict__ lens,
                                              ushort_t* __restrict__ Xp) {
    const int dir = blockIdx.z;
    const int tn = blockIdx.x;   // 0..7
    const int tm = blockIdx.y;   // 0..255

    // Length-aware tile skip: this tile covers b = tm>>2,
    // t in [(tm&3)*128, +128). k_rec never reads rows t >= len.
    {
        int lenb = lens[tm >> 2];
        if (lenb > 512) lenb = 512;
        if ((tm & 3) * 128 >= lenb) return;   // block-uniform branch
    }

    const ushort_t* Bmat = Bw + dir * 262144;
    const float* bv = biasv + dir * 1024;
    ushort_t* C = Xp + (size_t)dir * 33554432;
    const int tid = threadIdx.x;
    const int w = tid >> 6, l = tid & 63;
    const int wm = w & 1, wn = w >> 1;

    __shared__ ushort_t As[2][4096] __attribute__((aligned(16)));
    __shared__ ushort_t Bs[2][4096] __attribute__((aligned(16)));

    f32x4 acc[4][4];
    #pragma unroll
    for (int i = 0; i < 4; i++)
        #pragma unroll
        for (int jj = 0; jj < 4; jj++) acc[i][jj] = (f32x4){0.f, 0.f, 0.f, 0.f};

    // Staging geometry: thread tid covers rows {r0, r0+64}, LDS col-chunk cb.
    // Source col-chunk cs = (cb - (r0>>1)) & 3 (same for both row halves).
    const int r0 = tid >> 2, cb = tid & 3;
    const int cs = (cb - (r0 >> 1)) & 3;
    const ushort_t* Arow0 = &A[(size_t)(tm * 128 + r0) * 256 + cs * 8];
    const ushort_t* Arow1 = Arow0 + (size_t)64 * 256;
    const ushort_t* Brow0 = &Bmat[(size_t)(tn * 128 + r0) * 256 + cs * 8];
    const ushort_t* Brow1 = Brow0 + (size_t)64 * 256;
    const int lw = w * 512;   // wave-uniform LDS base (ushorts); lane at +l*16B

#define GISSUE(KB, CUR)                                   \
    async_load16(Arow0 + (KB) * 32, &As[CUR][lw]);        \
    async_load16(Arow1 + (KB) * 32, &As[CUR][2048 + lw]); \
    async_load16(Brow0 + (KB) * 32, &Bs[CUR][lw]);        \
    async_load16(Brow1 + (KB) * 32, &Bs[CUR][2048 + lw]);

#define GCOMPUTE(CUR)                                                         \
    {                                                                         \
        short8 af[4], bfr[4];                                                 \
        const int q = l >> 4;                                                 \
        _Pragma("unroll")                                                     \
        for (int mt = 0; mt < 4; mt++) {                                      \
            int rr = wm * 64 + mt * 16 + (l & 15);                            \
            af[mt] = *(const short8*)&As[CUR][LDSOFF(rr, q)];                 \
        }                                                                     \
        _Pragma("unroll")                                                     \
        for (int nt = 0; nt < 4; nt++) {                                      \
            int rr = wn * 64 + nt * 16 + (l & 15);                            \
            bfr[nt] = *(const short8*)&Bs[CUR][LDSOFF(rr, q)];                \
        }                                                                     \
        _Pragma("unroll")                                                     \
        for (int mt = 0; mt < 4; mt++)                                        \
            _Pragma("unroll")                                                 \
            for (int nt = 0; nt < 4; nt++)                                    \
                acc[mt][nt] = __builtin_amdgcn_mfma_f32_16x16x32_bf16(        \
                    af[mt], bfr[nt], acc[mt][nt], 0, 0, 0);                   \
    }

// One pipeline step: wait own oldest loads (counted, not 0) + barrier in a
// single asm (memory clobber: ds_reads can't slip above the barrier), then
// compute, then lgkm-barrier (all reads of CUR done), then refill CUR.
#define GSTEP(KB, CUR, VML, DOISSUE)                                          \
    asm volatile("s_waitcnt vmcnt(" VML ")\n\ts_barrier" ::: "memory");       \
    GCOMPUTE(CUR);                                                            \
    lds_barrier();                                                            \
    if (DOISSUE) { GISSUE((KB) + 2, CUR) }

    GISSUE(0, 0)
    GISSUE(1, 1)
    GSTEP(0, 0, "4", 1)
    GSTEP(1, 1, "4", 1)
    GSTEP(2, 0, "4", 1)
    GSTEP(3, 1, "4", 1)
    GSTEP(4, 0, "4", 1)
    GSTEP(5, 1, "4", 1)
    GSTEP(6, 0, "4", 0)
    GSTEP(7, 1, "0", 0)
#undef GSTEP
#undef GCOMPUTE
#undef GISSUE

    #pragma unroll
    for (int nt = 0; nt < 4; nt++) {
        int n = tn * 128 + wn * 64 + nt * 16 + (l & 15);
        float bn = bv[n];
        #pragma unroll
        for (int mt = 0; mt < 4; mt++) {
            #pragma unroll
            for (int rr = 0; rr < 4; rr++) {
                int m = tm * 128 + wm * 64 + mt * 16 + (l >> 4) * 4 + rr;
                C[(size_t)m * 1024 + n] = f2bf(acc[mt][nt][rr] + bn);
            }
        }
    }
}

// ---------------------------------------------------------------------------
// k_rec: recurrence (R8 champion, frozen). grid (64 b, 2 dir) x 512 thr.
// Wave w owns M-tiles w*8..w*8+7; lane l: rg=l>>4, til=l&7; active lanes
// ((l&15)<8) each own unit j=(w*8+til)*4+rg and hold its c_state.
__global__ __launch_bounds__(512, 2) void k_rec(const ushort_t* __restrict__ xproj,
                                                const int* __restrict__ wmf,
                                                const float* __restrict__ fscale4,
                                                const int* __restrict__ lens,
                                                float* __restrict__ out) {
    const int b = blockIdx.x, d = blockIdx.y;
    const int tid = threadIdx.x;
    const int w = tid >> 6, l = tid & 63;
    int len = lens[b];
    if (len < 1) len = 1;
    if (len > 512) len = 512;
    const int lenm1 = len - 1;
    const bool dneg = (d != 0);
    const ushort_t* xp = xproj + ((size_t)d * 64 + b) * 524288;  // 512*1024

    const int rg = l >> 4;            // 0..3
    const int rg16 = rg * 16;
    const int til = l & 7;
    const bool act = (l & 15) < 8;
    const int j = (w * 8 + til) * 4 + rg;   // unit 0..255

    // 32 A-fragments (128 dwords) pinned in VGPRs.
    i32x4 wf[8][4];
    const int* wb = wmf + d * 65536;
    #pragma unroll
    for (int i = 0; i < 8; i++)
        #pragma unroll
        for (int kt = 0; kt < 4; kt++)
            wf[i][kt] = *(const i32x4*)&wb[(((w * 8 + i) * 4 + kt) * 64 + l) * 4];
    #pragma unroll
    for (int i = 0; i < 8; i++)
        #pragma unroll
        for (int kt = 0; kt < 4; kt++)
            asm volatile("" : "+v"(wf[i][kt]));

    float4 fr = *(const float4*)&fscale4[d * 1024 + 4 * j];   // loop-invariant

    __shared__ char h8[2][256] __attribute__((aligned(16)));
    if (tid < 64) ((int*)h8)[tid] = 0;   // zero h8[0]

    // zero-fill this direction's half for t in [len, 512)
    {
        float4 z = {0.f, 0.f, 0.f, 0.f};
        int total4 = (512 - len) * 64;
        for (int i = tid; i < total4; i += 512) {
            int t = len + (i >> 6);
            int c4 = i & 63;
            *(float4*)&out[((size_t)b * 512 + t) * 512 + d * 256 + c4 * 4] = z;
        }
    }
    __syncthreads();

    float c_state = 0.0f;
    const i32x4 z4 = {0, 0, 0, 0};
    // lane-fixed byte pointers; per-step offsets are wave-uniform t*2048.
    const char* const xpl = (const char*)(xp + 4 * j);             // x row t: +t*2048
    char* const outl = (char*)(out + (size_t)b * 262144 + d * 256 + j);  // row t: +t*2048

    // x values for steps s and s+1 (loaded 2 steps ahead, no rotation movs).
    uint2 xe = *(const uint2*)(xpl + (size_t)(dneg ? lenm1 : 0) * 2048);
    uint2 xo;
    {
        int sc = (1 < lenm1) ? 1 : lenm1;
        xo = *(const uint2*)(xpl + (size_t)(dneg ? (lenm1 - sc) : sc) * 2048);
    }

    // One recurrence step at compile-time h8 parity (RB -> read, WB -> write).
    // XREG holds x for this step; it is reloaded with step S+2's row.
#define REC_STEP(RB, WB, XREG, S)                                              \
    do {                                                                       \
        const char* hbp = (const char*)h8[RB];                                 \
        i32x4 h0 = *(const i32x4*)(hbp + rg16);                                \
        i32x4 h1 = *(const i32x4*)(hbp + 64 + rg16);                           \
        i32x4 h2 = *(const i32x4*)(hbp + 128 + rg16);                          \
        i32x4 h3 = *(const i32x4*)(hbp + 192 + rg16);                          \
        uint2 xc = XREG;                                                       \
        {                                                                      \
            int sc2 = (S) + 2; if (sc2 > lenm1) sc2 = lenm1;                   \
            int t2 = dneg ? (lenm1 - sc2) : sc2;                               \
            XREG = *(const uint2*)(xpl + (size_t)t2 * 2048);                   \
        }                                                                      \
        i32x4 acc[8];                                                          \
        _Pragma("unroll")                                                      \
        for (int i = 0; i < 8; i++)                                            \
            acc[i] = __builtin_amdgcn_mfma_i32_16x16x64_i8(wf[i][0], h0, z4, 0, 0, 0); \
        _Pragma("unroll")                                                      \
        for (int i = 0; i < 8; i++)                                            \
            acc[i] = __builtin_amdgcn_mfma_i32_16x16x64_i8(wf[i][1], h1, acc[i], 0, 0, 0); \
        _Pragma("unroll")                                                      \
        for (int i = 0; i < 8; i++)                                            \
            acc[i] = __builtin_amdgcn_mfma_i32_16x16x64_i8(wf[i][2], h2, acc[i], 0, 0, 0); \
        _Pragma("unroll")                                                      \
        for (int i = 0; i < 8; i++)                                            \
            acc[i] = __builtin_amdgcn_mfma_i32_16x16x64_i8(wf[i][3], h3, acc[i], 0, 0, 0); \
        if (act) {                                                             \
            i32x4 q0 = (til & 1) ? acc[1] : acc[0];                            \
            i32x4 q1 = (til & 1) ? acc[3] : acc[2];                            \
            i32x4 q2 = (til & 1) ? acc[5] : acc[4];                            \
            i32x4 q3 = (til & 1) ? acc[7] : acc[6];                            \
            i32x4 r0 = (til & 2) ? q1 : q0;                                    \
            i32x4 r1 = (til & 2) ? q3 : q2;                                    \
            i32x4 u  = (til & 4) ? r1 : r0;                                    \
            float pi = bf2f((ushort_t)(xc.x & 0xffffu)) + fr.x * (float)u.x;   \
            float pf = bf2f((ushort_t)(xc.x >> 16))     + fr.y * (float)u.y;   \
            float pg = bf2f((ushort_t)(xc.y & 0xffffu)) + fr.z * (float)u.z;   \
            float po = bf2f((ushort_t)(xc.y >> 16))     + fr.w * (float)u.w;   \
            float ig = fsig(pi), fg = fsig(pf), gg = ftanh(pg), og = fsig(po); \
            c_state = fg * c_state + ig * gg;                                  \
            float h = og * ftanh(c_state);                                     \
            int qq = __float2int_rn(h * 127.0f);                               \
            qq = min(127, max(-127, qq));                                      \
            h8[WB][j] = (char)qq;                                              \
            int t = dneg ? (lenm1 - (S)) : (S);                                \
            *(float*)(outl + (size_t)t * 2048) = h;                            \
        }                                                                      \
        lds_barrier();                                                         \
    } while (0)

    int s = 0;
    for (; s + 1 < len; s += 2) {
        REC_STEP(0, 1, xe, s);
        REC_STEP(1, 0, xo, s + 1);
    }
    if (len & 1) {
        REC_STEP(0, 1, xe, s);
    }
#undef REC_STEP
}

// ---------------------------------------------------------------------------
extern "C" void kernel_launch(void* const* d_in, const int* in_sizes, int n_in,
                              void* d_out, int out_size, void* d_ws, size_t ws_size,
                              hipStream_t stream) {
    (void)in_sizes; (void)n_in; (void)out_size;
    const float* x    = (const float*)d_in[0];
    const int*   lens = (const int*)d_in[1];
    const float* wihf = (const float*)d_in[2];
    const float* whhf = (const float*)d_in[3];
    const float* bihf = (const float*)d_in[4];
    const float* bhhf = (const float*)d_in[5];
    const float* wihb = (const float*)d_in[6];
    const float* whhb = (const float*)d_in[7];
    const float* bihb = (const float*)d_in[8];
    const float* bhhb = (const float*)d_in[9];
    float* out = (float*)d_out;

    char* ws = (char*)d_ws;
    ushort_t* xbf    = (ushort_t*)(ws + 0);          //  16,777,216 B
    ushort_t* wihbf  = (ushort_t*)(ws + 16777216);   //   1,048,576 B
    float*    biasv  = (float*)(ws + 17825792);      //       8,192 B
    int*      wmf    = (int*)(ws + 17833984);        //     524,288 B
    float*    fscale4= (float*)(ws + 18358272);      //       8,192 B
    ushort_t* xproj  = (ushort_t*)(ws + 18366464);   // 134,217,728 B
    const size_t REQ = 18366464 + 134217728ull;
    if (ws_size < REQ) {
        fprintf(stderr, "kernel_launch: ws too small: %zu < %zu\n", ws_size, REQ);
    }

    k_f2bf<<<8192, 256, 0, stream>>>(x, xbf, 8388608);
    k_prep2<<<1032, 256, 0, stream>>>(wihf, wihb, wihbf,
                                      bihf, bhhf, bihb, bhhb, biasv,
                                      whhf, whhb, wmf, fscale4);
    k_gemm<<<dim3(8, 256, 2), 256, 0, stream>>>(xbf, wihbf, biasv, lens, xproj);
    k_rec<<<dim3(64, 2), 512, 0, stream>>>(xproj, wmf, fscale4, lens, out);
}